// Round 5
// baseline (275.166 us; speedup 1.0000x reference)
//
#include <hip/hip_runtime.h>

typedef unsigned short u16;
typedef unsigned int u32;
typedef __bf16 bf16x8 __attribute__((ext_vector_type(8)));
typedef __bf16 bf16x4 __attribute__((ext_vector_type(4)));
typedef short s16x4 __attribute__((ext_vector_type(4)));
typedef float f32x4 __attribute__((ext_vector_type(4)));
typedef float f32x16 __attribute__((ext_vector_type(16)));
typedef unsigned int u32x2 __attribute__((ext_vector_type(2)));
typedef unsigned int u32x4 __attribute__((ext_vector_type(4)));

struct __align__(8) u16x4 { u16 x, y, z, w; };

__device__ __forceinline__ void async_copy16(const void* g, void* l) {
  __builtin_amdgcn_global_load_lds(
      (__attribute__((address_space(1))) void*)g,
      (__attribute__((address_space(3))) void*)l, 16, 0, 0);
}

__device__ __forceinline__ u16 f2bf(float f) {
  unsigned u = __builtin_bit_cast(unsigned, f);
  u = (u + 0x7FFFu + ((u >> 16) & 1u)) >> 16;
  return (u16)u;
}
__device__ __forceinline__ float bf2f(u16 h) {
  unsigned u = ((unsigned)h) << 16;
  return __builtin_bit_cast(float, u);
}

// NOTE: call amdgcn builtins DIRECTLY — host pass parses aux-target builtins,
// but __has_builtin() is false for them on host (round-3 compile failure).
__device__ __forceinline__ float fast_exp2(float x) {
  return __builtin_amdgcn_exp2f(x);
}
__device__ __forceinline__ float fast_rcp(float x) {
  return __builtin_amdgcn_rcpf(x);
}

__device__ __forceinline__ f32x4 mfma32(bf16x8 a, bf16x8 b, f32x4 c) {
  return __builtin_amdgcn_mfma_f32_16x16x32_bf16(a, b, c, 0, 0, 0);
}

// packed f32 pair -> 1 u32 of 2x bf16 (low = first arg). No builtin on gfx950.
__device__ __forceinline__ u32 cvt_pk_bf16(float lo, float hi) {
  u32 r;
  asm("v_cvt_pk_bf16_f32 %0, %1, %2" : "=v"(r) : "v"(lo), "v"(hi));
  return r;
}

// SCALE * log2(e), folded into Q at the gemm1 epilogue.
#define CEXP 0.18033688011112042f

// ---------------------------------------------------------------------------
// Mode detection (bf16 vs fp32 inputs) — see round-1 notes. flag=0 -> fp32.
// ---------------------------------------------------------------------------
__global__ void detect_mode(const u32* __restrict__ probe, int* __restrict__ flag) {
  __shared__ int cnt[256];
  int t = threadIdx.x;
  int c = 0;
#pragma unroll
  for (int j = 0; j < 16; ++j) {
    u32 v = probe[t + j * 256];
    unsigned e = (v >> 7) & 0xFFu;
    c += (e >= 100u && e <= 130u) ? 1 : 0;
  }
  cnt[t] = c;
  __syncthreads();
  for (int s = 128; s > 0; s >>= 1) {
    if (t < s) cnt[t] += cnt[t + s];
    __syncthreads();
  }
  if (t == 0) *flag = (cnt[0] * 2 > 4096) ? 1 : 0;
}

__global__ void convert_in(const void* __restrict__ src, u16* __restrict__ dst,
                           const int* __restrict__ flag, int n) {
  int mode = *flag;
  int i = (blockIdx.x * blockDim.x + threadIdx.x) * 8;
  if (i >= n) return;
  if (mode == 1) {
    *(uint4*)(dst + i) = *(const uint4*)((const u16*)src + i);
  } else {
    const float* s = (const float*)src;
    float4 a = *(const float4*)(s + i);
    float4 b = *(const float4*)(s + i + 4);
    uint4 o;
    o.x = (u32)f2bf(a.x) | ((u32)f2bf(a.y) << 16);
    o.y = (u32)f2bf(a.z) | ((u32)f2bf(a.w) << 16);
    o.z = (u32)f2bf(b.x) | ((u32)f2bf(b.y) << 16);
    o.w = (u32)f2bf(b.z) | ((u32)f2bf(b.w) << 16);
    *(uint4*)(dst + i) = o;
  }
}

// ---------------------------------------------------------------------------
// NT GEMM, 256 x (NJ*64) tile, BK=64.
// Round-4 post-mortem: phase granularity must scale with NJ. NJ=3 (QKV):
// 4-phase (6 MFMA + 4 ds_read per phase) measured 111 -> <81 us. NJ=2
// (proj): 4-phase leaves only 8 MFMA per barrier pair and regressed (~+35us,
// inferred from the total); revert NJ=2 to the round-3 2-phase body (16
// MFMA/phase, numerically validated in round 3).
// Shared: QKV 16x32=512 blk = 2 exact rounds (112KB LDS); proj 8x32=256 =
// 1 round (96KB). Bijective XCD swizzle; counted vmcnt(NJ+4) once per
// K-tile (never 0 in steady state); T2 XOR swizzle both-sides, 0 conflicts.
// Epilogue per-column: BN=192 tiles straddle Q|K|V boundaries (1024/2048).
// ---------------------------------------------------------------------------
template<int NJ>
__global__ __launch_bounds__(512, 2) void gemm_bt(
    const u16* __restrict__ A, const u16* __restrict__ Bm,
    u16* __restrict__ C, u16* __restrict__ vT, const u16* __restrict__ bias,
    float* __restrict__ outF, const int* __restrict__ flagp,
    int K, int ldc)
{
  // A dbuf [2][256][64] @0 (64KB); B dbuf [2][NJ*64][64] @65536.
  __shared__ __align__(16) char lds[65536 + NJ * 16384];

  const int t = threadIdx.x;
  const int lane = t & 63, wave = t >> 6;
  const int quad = lane >> 4, l16 = lane & 15;
  const int wn = wave & 3, wm = wave >> 2;

  // XCD-chunked bijective remap: blocks with equal rowbase share an XCD.
  const int nwg = gridDim.x * gridDim.y;
  int bid = blockIdx.y * gridDim.x + blockIdx.x;
  bid = (bid & 7) * (nwg >> 3) + (bid >> 3);
  const int rowbase = (bid / gridDim.x) * 256;
  const int colbase = (bid % gridDim.x) * (NJ * 64);

  // staging: thread t covers LDS linear bytes q*8192 + t*16 of each region.
  const int srow = t >> 3;
  const int scol = ((t & 7) << 4) ^ ((srow & 7) << 4);
  const int wlds = wave << 10;

  const u16* Arow = A + (size_t)(rowbase + srow) * K + (scol >> 1);
  const u16* Brow = Bm + (size_t)(colbase + srow) * K + (scol >> 1);

  auto stageA = [&](int kb_, int buf_) {
#pragma unroll
    for (int q = 0; q < 4; ++q)
      async_copy16(Arow + (size_t)kb_ * 64 + (size_t)q * 64 * K,
                   lds + buf_ * 32768 + q * 8192 + wlds);
  };
  auto stageB = [&](int kb_, int buf_) {
#pragma unroll
    for (int q = 0; q < NJ; ++q)
      async_copy16(Brow + (size_t)kb_ * 64 + (size_t)q * 64 * K,
                   lds + 65536 + buf_ * (NJ * 8192) + q * 8192 + wlds);
  };

  f32x4 acc[8][NJ] = {};

  // fragment-read bases; row byte-swizzle uses row&7 == l16&7.
  const int swzl = (l16 & 7) << 4;
  const int c0 = (quad * 16) ^ swzl;          // k-half 0 (k 0..31)
  const int c1 = (64 + quad * 16) ^ swzl;     // k-half 1 (k 32..63)
  const char* Ard = lds + (size_t)(wm * 128 + l16) * 128;
  const char* Brd = lds + 65536 + (size_t)(wn * (NJ * 16) + l16) * 128;

  // prologue: tile0 -> buf0, tile1 -> buf1; drain tile0, keep tile1 in flight.
  stageA(0, 0); stageB(0, 0);
  stageA(1, 1); stageB(1, 1);
  if constexpr (NJ == 3) asm volatile("s_waitcnt vmcnt(7)" ::: "memory");
  else                   asm volatile("s_waitcnt vmcnt(6)" ::: "memory");
  __builtin_amdgcn_s_barrier();

  const int nkb = K >> 6;
  for (int kb = 0; kb < nkb; ++kb) {
    const int cur = kb & 1;
    const char* Ab = Ard + cur * 32768;
    const char* Bb = Brd + cur * (NJ * 8192);

    if constexpr (NJ == 2) {
      // ---- 2-phase body (round-3 validated; 16 MFMA per phase) ----
      bf16x8 aR[4][2], bR[2][2];
#pragma unroll
      for (int i = 0; i < 4; ++i) {
        aR[i][0] = *(const bf16x8*)(Ab + i * 2048 + c0);
        aR[i][1] = *(const bf16x8*)(Ab + i * 2048 + c1);
      }
#pragma unroll
      for (int j = 0; j < 2; ++j) {
        bR[j][0] = *(const bf16x8*)(Bb + j * 2048 + c0);
        bR[j][1] = *(const bf16x8*)(Bb + j * 2048 + c1);
      }
      __builtin_amdgcn_s_barrier();
      __builtin_amdgcn_s_setprio(1);
#pragma unroll
      for (int i = 0; i < 4; ++i)
#pragma unroll
        for (int j = 0; j < 2; ++j) {
          acc[i][j] = mfma32(aR[i][0], bR[j][0], acc[i][j]);
          acc[i][j] = mfma32(aR[i][1], bR[j][1], acc[i][j]);
        }
      __builtin_amdgcn_s_setprio(0);
      __builtin_amdgcn_s_barrier();
      if (kb + 2 < nkb) stageB(kb + 2, cur);

#pragma unroll
      for (int i = 0; i < 4; ++i) {
        aR[i][0] = *(const bf16x8*)(Ab + 8192 + i * 2048 + c0);
        aR[i][1] = *(const bf16x8*)(Ab + 8192 + i * 2048 + c1);
      }
      __builtin_amdgcn_s_barrier();
      __builtin_amdgcn_s_setprio(1);
#pragma unroll
      for (int i = 0; i < 4; ++i)
#pragma unroll
        for (int j = 0; j < 2; ++j) {
          acc[4 + i][j] = mfma32(aR[i][0], bR[j][0], acc[4 + i][j]);
          acc[4 + i][j] = mfma32(aR[i][1], bR[j][1], acc[4 + i][j]);
        }
      __builtin_amdgcn_s_setprio(0);
      __builtin_amdgcn_s_barrier();
    } else {
      // ---- 4-phase body (round-4 validated for NJ=3; 12 MFMA per phase) ----
      bf16x8 aR[4], bR[NJ][2];

      // phase 1: A-half0/k0 + ALL B (B cached in regs for the K-tile)
#pragma unroll
      for (int i = 0; i < 4; ++i) aR[i] = *(const bf16x8*)(Ab + i * 2048 + c0);
#pragma unroll
      for (int j = 0; j < NJ; ++j) {
        bR[j][0] = *(const bf16x8*)(Bb + j * 2048 + c0);
        bR[j][1] = *(const bf16x8*)(Bb + j * 2048 + c1);
      }
      __builtin_amdgcn_s_barrier();
      __builtin_amdgcn_s_setprio(1);
#pragma unroll
      for (int i = 0; i < 4; ++i)
#pragma unroll
        for (int j = 0; j < NJ; ++j)
          acc[i][j] = mfma32(aR[i], bR[j][0], acc[i][j]);
      __builtin_amdgcn_s_setprio(0);
      __builtin_amdgcn_s_barrier();

      // phase 2: A-half0/k1
#pragma unroll
      for (int i = 0; i < 4; ++i) aR[i] = *(const bf16x8*)(Ab + i * 2048 + c1);
      __builtin_amdgcn_s_barrier();
      __builtin_amdgcn_s_setprio(1);
#pragma unroll
      for (int i = 0; i < 4; ++i)
#pragma unroll
        for (int j = 0; j < NJ; ++j)
          acc[i][j] = mfma32(aR[i], bR[j][1], acc[i][j]);
      __builtin_amdgcn_s_setprio(0);
      __builtin_amdgcn_s_barrier();
      if (kb + 2 < nkb) stageB(kb + 2, cur);   // B LDS region fully consumed

      // phase 3: A-half1/k1
#pragma unroll
      for (int i = 0; i < 4; ++i) aR[i] = *(const bf16x8*)(Ab + 8192 + i * 2048 + c1);
      __builtin_amdgcn_s_barrier();
      __builtin_amdgcn_s_setprio(1);
#pragma unroll
      for (int i = 0; i < 4; ++i)
#pragma unroll
        for (int j = 0; j < NJ; ++j)
          acc[4 + i][j] = mfma32(aR[i], bR[j][1], acc[4 + i][j]);
      __builtin_amdgcn_s_setprio(0);
      __builtin_amdgcn_s_barrier();

      // phase 4: A-half1/k0
#pragma unroll
      for (int i = 0; i < 4; ++i) aR[i] = *(const bf16x8*)(Ab + 8192 + i * 2048 + c0);
      __builtin_amdgcn_s_barrier();
      __builtin_amdgcn_s_setprio(1);
#pragma unroll
      for (int i = 0; i < 4; ++i)
#pragma unroll
        for (int j = 0; j < NJ; ++j)
          acc[4 + i][j] = mfma32(aR[i], bR[j][0], acc[4 + i][j]);
      __builtin_amdgcn_s_setprio(0);
      __builtin_amdgcn_s_barrier();
    }

    if (kb + 2 < nkb) {
      stageA(kb + 2, cur);                    // A region fully consumed
      if constexpr (NJ == 3) asm volatile("s_waitcnt vmcnt(7)" ::: "memory");
      else                   asm volatile("s_waitcnt vmcnt(6)" ::: "memory");
      __builtin_amdgcn_s_barrier();
    } else if (kb + 1 < nkb) {
      asm volatile("s_waitcnt vmcnt(0)" ::: "memory");
      __builtin_amdgcn_s_barrier();
    }
  }

  // ---- epilogue, per-column (tiles straddle Q|K|V boundaries).
  const bool f32out = (flagp != nullptr) && (*flagp == 0);
#pragma unroll
  for (int nj = 0; nj < NJ; ++nj) {
    int cg = colbase + wn * (NJ * 16) + nj * 16 + l16;
    if (vT != nullptr && cg >= 2048) {
      // V section -> per-head transposed store
#pragma unroll
      for (int mi = 0; mi < 8; ++mi) {
        int rg = rowbase + wm * 128 + mi * 16 + quad * 4;
        int b = rg >> 11, n = rg & 2047;
        size_t idx = ((size_t)(b * 1024 + (cg - 2048))) * 2048 + n;
        u16x4 pk;
        pk.x = f2bf(acc[mi][nj][0]); pk.y = f2bf(acc[mi][nj][1]);
        pk.z = f2bf(acc[mi][nj][2]); pk.w = f2bf(acc[mi][nj][3]);
        *(u16x4*)(vT + idx) = pk;
      }
    } else {
      const float scl = (vT != nullptr && cg < 1024) ? CEXP : 1.0f;
      float bv = bias ? bf2f(bias[cg]) : 0.0f;
#pragma unroll
      for (int mi = 0; mi < 8; ++mi) {
#pragma unroll
        for (int r = 0; r < 4; ++r) {
          int rg = rowbase + wm * 128 + mi * 16 + quad * 4 + r;
          float val = acc[mi][nj][r] * scl + bv;
          if (f32out) outF[(size_t)rg * ldc + cg] = val;
          else        C[(size_t)rg * ldc + cg] = f2bf(val);
        }
      }
    }
  }
}

// ---------------------------------------------------------------------------
// Flash attention — 32x32 MFMA structure. Round-5 changes:
//   - ones-MFMA denominator: o3 = mfma(fa, ones) accumulates row sums of P
//     in the MFMA pipe (4 extra mfma/tile), deleting the serial 32-add lsum
//     chain per tile from the VALU pipe AND the end-of-kernel shuffle
//     reduce (o3 rows share o2's query mapping — lane-local rcp).
//     Denominator now sums the SAME bf16 P as the numerator (weights sum
//     to 1 consistently).
//   - counted staging (GEMM T4 pattern): s_barrier (nxt reuse safe: all
//     reads of nxt were consumed pre-barrier) -> issue 4 loads->nxt ->
//     vmcnt(4) (own cur loads landed, nxt in flight) -> s_barrier (ALL
//     waves' cur data resident) -> compute. Replaces __syncthreads' full
//     vmcnt(0)+lgkm(0) drain; never drains to 0 in steady state.
// Bank conflicts (8.4M) left alone: pattern is 2 lanes/bank per 16-lane
// phase = bandwidth floor; m136 says 2-way is free (counter counts anyway).
// ---------------------------------------------------------------------------
__global__ __launch_bounds__(256, 4) void attn_fwd(
    const u16* __restrict__ qk, const u16* __restrict__ vT, u16* __restrict__ outp)
{
  __shared__ __align__(16) char sm[32768];  // K[2][8192] | V[2][8192]

  const int t = threadIdx.x;
  const int lane = t & 63, wave = t >> 6;
  const int l31 = lane & 31, h32 = lane >> 5;
  const int bh = blockIdx.x, b = bh >> 4, h = bh & 15;
  const int qtile = blockIdx.y;
  const size_t row0 = (size_t)b * 2048;
  const int qb = qtile * 128 + wave * 32;

  bf16x8 qf[4];
  {
    const u16* qp = qk + (row0 + qb + l31) * 2048 + h * 64 + h32 * 8;
#pragma unroll
    for (int s = 0; s < 4; ++s)
      qf[s] = *(const bf16x8*)(qp + s * 16);
  }

  const u16* Kg[2]; const u16* Vg[2]; unsigned loff[2];
#pragma unroll
  for (int q = 0; q < 2; ++q) {
    int si = q * 256 + t;
    int srow = si >> 3;
    int scolb = ((si & 7) << 4) ^ ((srow & 7) << 4);
    Kg[q] = qk + (row0 + srow) * 2048 + 1024 + h * 64 + (scolb >> 1);
    Vg[q] = vT + ((size_t)(b * 1024 + h * 64 + srow)) * 2048 + (scolb >> 1);
    loff[q] = q * 4096 + wave * 1024;
  }

#pragma unroll
  for (int q = 0; q < 2; ++q) {
    async_copy16(Kg[q], sm + loff[q]);
    async_copy16(Vg[q], sm + 16384 + loff[q]);
  }

  const int swz = (lane & 7) << 4;
  int cswz[4];
#pragma unroll
  for (int s = 0; s < 4; ++s) cswz[s] = (s * 32 + h32 * 16) ^ swz;
  const int rowb = l31 * 128;

  // bf16 1.0 broadcast for the denominator MFMA
  u32x4 onev; onev.x = 0x3F803F80u; onev.y = 0x3F803F80u;
  onev.z = 0x3F803F80u; onev.w = 0x3F803F80u;
  const bf16x8 ones = __builtin_bit_cast(bf16x8, onev);

  f32x16 o2[2] = {};
  f32x16 o3 = {};   // row sums of P (denominator), same layout as o2

  for (int kb = 0; kb < 32; ++kb) {
    const int cur = kb & 1, nxt = cur ^ 1;
    // barrier 1: every wave consumed its reads of buf[nxt] (iter kb-1)
    __builtin_amdgcn_s_barrier();
    if (kb < 31) {
#pragma unroll
      for (int q = 0; q < 2; ++q) {
        async_copy16(Kg[q] + (size_t)(kb + 1) * 64 * 2048, sm + nxt * 8192 + loff[q]);
        async_copy16(Vg[q] + (kb + 1) * 64, sm + 16384 + nxt * 8192 + loff[q]);
      }
      asm volatile("s_waitcnt vmcnt(4)" ::: "memory");  // own cur loads landed
    } else {
      asm volatile("s_waitcnt vmcnt(0)" ::: "memory");
    }
    // barrier 2: ALL waves' cur loads landed -> buf[cur] fully resident
    __builtin_amdgcn_s_barrier();

    const char* Kb = sm + cur * 8192;
    const char* Vb = sm + 16384 + cur * 8192;

#pragma unroll
    for (int kh = 0; kh < 2; ++kh) {
      f32x16 s2 = {};
      __builtin_amdgcn_s_setprio(1);
#pragma unroll
      for (int s = 0; s < 4; ++s) {
        bf16x8 kf = *(const bf16x8*)(Kb + kh * 4096 + rowb + cswz[s]);
        s2 = __builtin_amdgcn_mfma_f32_32x32x16_bf16(kf, qf[s], s2, 0, 0, 0);
      }
      __builtin_amdgcn_s_setprio(0);

      u32 u[8];
#pragma unroll
      for (int w = 0; w < 8; ++w) {
        float p0 = fast_exp2(s2[2 * w]);
        float p1 = fast_exp2(s2[2 * w + 1]);
        u[w] = cvt_pk_bf16(p0, p1);
      }

      u32x2 r02 = __builtin_amdgcn_permlane32_swap(u[0], u[2], false, false);
      u32x2 r13 = __builtin_amdgcn_permlane32_swap(u[1], u[3], false, false);
      u32x2 r46 = __builtin_amdgcn_permlane32_swap(u[4], u[6], false, false);
      u32x2 r57 = __builtin_amdgcn_permlane32_swap(u[5], u[7], false, false);
      u32x4 fa0v; fa0v.x = r02.x; fa0v.y = r13.x; fa0v.z = r02.y; fa0v.w = r13.y;
      u32x4 fa1v; fa1v.x = r46.x; fa1v.y = r57.x; fa1v.z = r46.y; fa1v.w = r57.y;
      bf16x8 fa0 = __builtin_bit_cast(bf16x8, fa0v);   // keys kh*32 + 0..15
      bf16x8 fa1 = __builtin_bit_cast(bf16x8, fa1v);   // keys kh*32 + 16..31

      __builtin_amdgcn_s_setprio(1);
#pragma unroll
      for (int eb = 0; eb < 2; ++eb) {
        bf16x8 v0 = *(const bf16x8*)(Vb + eb * 4096 + rowb + cswz[kh * 2 + 0]);
        o2[eb] = __builtin_amdgcn_mfma_f32_32x32x16_bf16(fa0, v0, o2[eb], 0, 0, 0);
        bf16x8 v1 = *(const bf16x8*)(Vb + eb * 4096 + rowb + cswz[kh * 2 + 1]);
        o2[eb] = __builtin_amdgcn_mfma_f32_32x32x16_bf16(fa1, v1, o2[eb], 0, 0, 0);
      }
      // denominator: row sums of P via ones-column (MFMA pipe, no VALU chain)
      o3 = __builtin_amdgcn_mfma_f32_32x32x16_bf16(fa0, ones, o3, 0, 0, 0);
      o3 = __builtin_amdgcn_mfma_f32_32x32x16_bf16(fa1, ones, o3, 0, 0, 0);
      __builtin_amdgcn_s_setprio(0);
    }
  }

  // O layout: col(lane&31) = e, rows = queries (r&3)+8*(r>>2)+4*h32.
  // o3[r] already holds the full denominator for query qr (lane-local).
#pragma unroll
  for (int r = 0; r < 16; ++r) {
    int qr = (r & 3) + 8 * (r >> 2) + 4 * h32;
    float iv = fast_rcp(o3[r]);
    size_t base = (row0 + qb + qr) * 1024 + h * 64 + l31;
    outp[base]      = f2bf(o2[0][r] * iv);
    outp[base + 32] = f2bf(o2[1][r] * iv);
  }
}

// ---------------------------------------------------------------------------
// Workspace (u16 elems): qkbuf 16777216 | vT 8388608 | xb/attn 8388608 |
// wqkvb 3145728 | flag. wprojb/bprojb alias vT after attn_fwd.
// ---------------------------------------------------------------------------
extern "C" void kernel_launch(void* const* d_in, const int* in_sizes, int n_in,
                              void* d_out, int out_size, void* d_ws, size_t ws_size,
                              hipStream_t stream) {
  (void)in_sizes; (void)n_in; (void)out_size; (void)ws_size;
  const void* x_in     = d_in[0];
  const void* wqkv_in  = d_in[1];
  const void* wproj_in = d_in[2];
  const void* bproj_in = d_in[3];

  u16* qkbuf  = (u16*)d_ws;
  u16* vT     = qkbuf + 16777216;
  u16* xb     = vT + 8388608;
  u16* wqkvb  = xb + 8388608;
  int* flag   = (int*)(wqkvb + 3145728);
  u16* attn   = xb;
  u16* wprojb = vT;
  u16* bprojb = vT + 1048576;

  detect_mode<<<1, 256, 0, stream>>>((const u32*)wqkv_in, flag);
  convert_in<<<4096, 256, 0, stream>>>(x_in, xb, flag, 8388608);
  convert_in<<<1536, 256, 0, stream>>>(wqkv_in, wqkvb, flag, 3145728);

  // QKV: 256x192 tiles -> 16x32 = 512 blocks = 2 exact rounds (4-phase).
  gemm_bt<3><<<dim3(16, 32), 512, 0, stream>>>(xb, wqkvb, qkbuf, vT, nullptr,
                                               nullptr, nullptr, 1024, 2048);
  attn_fwd<<<dim3(64, 16), 256, 0, stream>>>(qkbuf, vT, attn);

  convert_in<<<512, 256, 0, stream>>>(wproj_in, wprojb, flag, 1048576);
  convert_in<<<1, 256, 0, stream>>>(bproj_in, bprojb, flag, 1024);

  // proj: 256x128 tiles -> 8x32 = 256 blocks = 1 exact round (2-phase).
  gemm_bt<2><<<dim3(8, 32), 512, 0, stream>>>(attn, wprojb, (u16*)d_out, nullptr,
                                              bprojb, (float*)d_out, flag, 1024, 1024);
}

// Round 6
// 269.442 us; speedup vs baseline: 1.0212x; 1.0212x over previous
//
#include <hip/hip_runtime.h>

typedef unsigned short u16;
typedef unsigned int u32;
typedef __bf16 bf16x8 __attribute__((ext_vector_type(8)));
typedef __bf16 bf16x4 __attribute__((ext_vector_type(4)));
typedef short s16x4 __attribute__((ext_vector_type(4)));
typedef float f32x4 __attribute__((ext_vector_type(4)));
typedef float f32x16 __attribute__((ext_vector_type(16)));
typedef unsigned int u32x2 __attribute__((ext_vector_type(2)));
typedef unsigned int u32x4 __attribute__((ext_vector_type(4)));

struct __align__(8) u16x4 { u16 x, y, z, w; };

__device__ __forceinline__ void async_copy16(const void* g, void* l) {
  __builtin_amdgcn_global_load_lds(
      (__attribute__((address_space(1))) void*)g,
      (__attribute__((address_space(3))) void*)l, 16, 0, 0);
}

__device__ __forceinline__ u16 f2bf(float f) {
  unsigned u = __builtin_bit_cast(unsigned, f);
  u = (u + 0x7FFFu + ((u >> 16) & 1u)) >> 16;
  return (u16)u;
}
__device__ __forceinline__ float bf2f(u16 h) {
  unsigned u = ((unsigned)h) << 16;
  return __builtin_bit_cast(float, u);
}

// NOTE: call amdgcn builtins DIRECTLY — host pass parses aux-target builtins,
// but __has_builtin() is false for them on host (round-3 compile failure).
__device__ __forceinline__ float fast_exp2(float x) {
  return __builtin_amdgcn_exp2f(x);
}
__device__ __forceinline__ float fast_rcp(float x) {
  return __builtin_amdgcn_rcpf(x);
}

__device__ __forceinline__ f32x4 mfma32(bf16x8 a, bf16x8 b, f32x4 c) {
  return __builtin_amdgcn_mfma_f32_16x16x32_bf16(a, b, c, 0, 0, 0);
}

// packed f32 pair -> 1 u32 of 2x bf16 (low = first arg). No builtin on gfx950.
__device__ __forceinline__ u32 cvt_pk_bf16(float lo, float hi) {
  u32 r;
  asm("v_cvt_pk_bf16_f32 %0, %1, %2" : "=v"(r) : "v"(lo), "v"(hi));
  return r;
}

// SCALE * log2(e), folded into Q at the gemm1 epilogue.
#define CEXP 0.18033688011112042f

// ---------------------------------------------------------------------------
// Mode detection (bf16 vs fp32 inputs) — see round-1 notes. flag=0 -> fp32.
// ---------------------------------------------------------------------------
__global__ void detect_mode(const u32* __restrict__ probe, int* __restrict__ flag) {
  __shared__ int cnt[256];
  int t = threadIdx.x;
  int c = 0;
#pragma unroll
  for (int j = 0; j < 16; ++j) {
    u32 v = probe[t + j * 256];
    unsigned e = (v >> 7) & 0xFFu;
    c += (e >= 100u && e <= 130u) ? 1 : 0;
  }
  cnt[t] = c;
  __syncthreads();
  for (int s = 128; s > 0; s >>= 1) {
    if (t < s) cnt[t] += cnt[t + s];
    __syncthreads();
  }
  if (t == 0) *flag = (cnt[0] * 2 > 4096) ? 1 : 0;
}

__global__ void convert_in(const void* __restrict__ src, u16* __restrict__ dst,
                           const int* __restrict__ flag, int n) {
  int mode = *flag;
  int i = (blockIdx.x * blockDim.x + threadIdx.x) * 8;
  if (i >= n) return;
  if (mode == 1) {
    *(uint4*)(dst + i) = *(const uint4*)((const u16*)src + i);
  } else {
    const float* s = (const float*)src;
    float4 a = *(const float4*)(s + i);
    float4 b = *(const float4*)(s + i + 4);
    uint4 o;
    o.x = (u32)f2bf(a.x) | ((u32)f2bf(a.y) << 16);
    o.y = (u32)f2bf(a.z) | ((u32)f2bf(a.w) << 16);
    o.z = (u32)f2bf(b.x) | ((u32)f2bf(b.y) << 16);
    o.w = (u32)f2bf(b.z) | ((u32)f2bf(b.w) << 16);
    *(uint4*)(dst + i) = o;
  }
}

// ---------------------------------------------------------------------------
// NT GEMM, 256 x (NJ*64) tile, BK=64.
// NJ=3 (QKV): 4-phase body (R4-validated), staging SPREAD per phase this
// round (m201 fidelity): B region is dead after ph1 (register-cached) ->
// stageB at ph1-close; A chunks q0/q2 dead after ph2 -> stage there; q1/q3
// after ph4; ONE vmcnt(7) per K-tile unchanged. NJ=2 (proj): 2-phase body
// (R3-validated; R5 showed 2-phase vs 4-phase proj is a wash, keep simpler).
// Shared: QKV 16x32=512 blk = 2 exact rounds (112KB); proj 8x32=256 = 1
// round (96KB); bijective XCD swizzle; T2 XOR swizzle both-sides (0 confl).
// Epilogue per-column: BN=192 tiles straddle Q|K|V boundaries (1024/2048).
// ---------------------------------------------------------------------------
template<int NJ>
__global__ __launch_bounds__(512, 2) void gemm_bt(
    const u16* __restrict__ A, const u16* __restrict__ Bm,
    u16* __restrict__ C, u16* __restrict__ vT, const u16* __restrict__ bias,
    float* __restrict__ outF, const int* __restrict__ flagp,
    int K, int ldc)
{
  // A dbuf [2][256][64] @0 (64KB); B dbuf [2][NJ*64][64] @65536.
  __shared__ __align__(16) char lds[65536 + NJ * 16384];

  const int t = threadIdx.x;
  const int lane = t & 63, wave = t >> 6;
  const int quad = lane >> 4, l16 = lane & 15;
  const int wn = wave & 3, wm = wave >> 2;

  // XCD-chunked bijective remap: blocks with equal rowbase share an XCD.
  const int nwg = gridDim.x * gridDim.y;
  int bid = blockIdx.y * gridDim.x + blockIdx.x;
  bid = (bid & 7) * (nwg >> 3) + (bid >> 3);
  const int rowbase = (bid / gridDim.x) * 256;
  const int colbase = (bid % gridDim.x) * (NJ * 64);

  // staging: thread t covers LDS linear bytes q*8192 + t*16 of each region.
  const int srow = t >> 3;
  const int scol = ((t & 7) << 4) ^ ((srow & 7) << 4);
  const int wlds = wave << 10;

  const u16* Arow = A + (size_t)(rowbase + srow) * K + (scol >> 1);
  const u16* Brow = Bm + (size_t)(colbase + srow) * K + (scol >> 1);

  // stage A chunks qa and qb (rows qa*64.., qb*64..) of k-tile kb_ into buf_
  auto stageA2 = [&](int kb_, int buf_, int qa, int qb2) {
    async_copy16(Arow + (size_t)kb_ * 64 + (size_t)qa * 64 * K,
                 lds + buf_ * 32768 + qa * 8192 + wlds);
    async_copy16(Arow + (size_t)kb_ * 64 + (size_t)qb2 * 64 * K,
                 lds + buf_ * 32768 + qb2 * 8192 + wlds);
  };
  auto stageA = [&](int kb_, int buf_) {
#pragma unroll
    for (int q = 0; q < 4; ++q)
      async_copy16(Arow + (size_t)kb_ * 64 + (size_t)q * 64 * K,
                   lds + buf_ * 32768 + q * 8192 + wlds);
  };
  auto stageB = [&](int kb_, int buf_) {
#pragma unroll
    for (int q = 0; q < NJ; ++q)
      async_copy16(Brow + (size_t)kb_ * 64 + (size_t)q * 64 * K,
                   lds + 65536 + buf_ * (NJ * 8192) + q * 8192 + wlds);
  };

  f32x4 acc[8][NJ] = {};

  // fragment-read bases; row byte-swizzle uses row&7 == l16&7.
  const int swzl = (l16 & 7) << 4;
  const int c0 = (quad * 16) ^ swzl;          // k-half 0 (k 0..31)
  const int c1 = (64 + quad * 16) ^ swzl;     // k-half 1 (k 32..63)
  const char* Ard = lds + (size_t)(wm * 128 + l16) * 128;
  const char* Brd = lds + 65536 + (size_t)(wn * (NJ * 16) + l16) * 128;

  // prologue: tile0 -> buf0, tile1 -> buf1; drain tile0, keep tile1 in flight.
  stageA(0, 0); stageB(0, 0);
  stageA(1, 1); stageB(1, 1);
  if constexpr (NJ == 3) asm volatile("s_waitcnt vmcnt(7)" ::: "memory");
  else                   asm volatile("s_waitcnt vmcnt(6)" ::: "memory");
  __builtin_amdgcn_s_barrier();

  const int nkb = K >> 6;
  for (int kb = 0; kb < nkb; ++kb) {
    const int cur = kb & 1;
    const char* Ab = Ard + cur * 32768;
    const char* Bb = Brd + cur * (NJ * 8192);
    const bool pf = (kb + 2 < nkb);

    if constexpr (NJ == 2) {
      // ---- 2-phase body (round-3 validated; 16 MFMA per phase) ----
      bf16x8 aR[4][2], bR[2][2];
#pragma unroll
      for (int i = 0; i < 4; ++i) {
        aR[i][0] = *(const bf16x8*)(Ab + i * 2048 + c0);
        aR[i][1] = *(const bf16x8*)(Ab + i * 2048 + c1);
      }
#pragma unroll
      for (int j = 0; j < 2; ++j) {
        bR[j][0] = *(const bf16x8*)(Bb + j * 2048 + c0);
        bR[j][1] = *(const bf16x8*)(Bb + j * 2048 + c1);
      }
      __builtin_amdgcn_s_barrier();
      __builtin_amdgcn_s_setprio(1);
#pragma unroll
      for (int i = 0; i < 4; ++i)
#pragma unroll
        for (int j = 0; j < 2; ++j) {
          acc[i][j] = mfma32(aR[i][0], bR[j][0], acc[i][j]);
          acc[i][j] = mfma32(aR[i][1], bR[j][1], acc[i][j]);
        }
      __builtin_amdgcn_s_setprio(0);
      __builtin_amdgcn_s_barrier();
      if (pf) stageB(kb + 2, cur);

#pragma unroll
      for (int i = 0; i < 4; ++i) {
        aR[i][0] = *(const bf16x8*)(Ab + 8192 + i * 2048 + c0);
        aR[i][1] = *(const bf16x8*)(Ab + 8192 + i * 2048 + c1);
      }
      __builtin_amdgcn_s_barrier();
      __builtin_amdgcn_s_setprio(1);
#pragma unroll
      for (int i = 0; i < 4; ++i)
#pragma unroll
        for (int j = 0; j < 2; ++j) {
          acc[4 + i][j] = mfma32(aR[i][0], bR[j][0], acc[4 + i][j]);
          acc[4 + i][j] = mfma32(aR[i][1], bR[j][1], acc[4 + i][j]);
        }
      __builtin_amdgcn_s_setprio(0);
      __builtin_amdgcn_s_barrier();

      if (pf) {
        stageA(kb + 2, cur);
        asm volatile("s_waitcnt vmcnt(6)" ::: "memory");
        __builtin_amdgcn_s_barrier();
      } else if (kb + 1 < nkb) {
        asm volatile("s_waitcnt vmcnt(0)" ::: "memory");
        __builtin_amdgcn_s_barrier();
      }
    } else {
      // ---- 4-phase body (R4-validated for NJ=3), staging spread 3/2/0/2 ----
      bf16x8 aR[4], bR[NJ][2];

      // phase 1: A-half0/k0 + ALL B (B cached in regs for the K-tile)
#pragma unroll
      for (int i = 0; i < 4; ++i) aR[i] = *(const bf16x8*)(Ab + i * 2048 + c0);
#pragma unroll
      for (int j = 0; j < NJ; ++j) {
        bR[j][0] = *(const bf16x8*)(Bb + j * 2048 + c0);
        bR[j][1] = *(const bf16x8*)(Bb + j * 2048 + c1);
      }
      __builtin_amdgcn_s_barrier();
      __builtin_amdgcn_s_setprio(1);
#pragma unroll
      for (int i = 0; i < 4; ++i)
#pragma unroll
        for (int j = 0; j < NJ; ++j)
          acc[i][j] = mfma32(aR[i], bR[j][0], acc[i][j]);
      __builtin_amdgcn_s_setprio(0);
      __builtin_amdgcn_s_barrier();
      if (pf) stageB(kb + 2, cur);   // B LDS region dead after ph1 (reg-cached)

      // phase 2: A-half0/k1 — closes reads of A chunks q0 (wm=0) / q2 (wm=1)
#pragma unroll
      for (int i = 0; i < 4; ++i) aR[i] = *(const bf16x8*)(Ab + i * 2048 + c1);
      __builtin_amdgcn_s_barrier();
      __builtin_amdgcn_s_setprio(1);
#pragma unroll
      for (int i = 0; i < 4; ++i)
#pragma unroll
        for (int j = 0; j < NJ; ++j)
          acc[i][j] = mfma32(aR[i], bR[j][1], acc[i][j]);
      __builtin_amdgcn_s_setprio(0);
      __builtin_amdgcn_s_barrier();
      if (pf) stageA2(kb + 2, cur, 0, 2);   // q0,q2 dead after ph2

      // phase 3: A-half1/k1
#pragma unroll
      for (int i = 0; i < 4; ++i) aR[i] = *(const bf16x8*)(Ab + 8192 + i * 2048 + c1);
      __builtin_amdgcn_s_barrier();
      __builtin_amdgcn_s_setprio(1);
#pragma unroll
      for (int i = 0; i < 4; ++i)
#pragma unroll
        for (int j = 0; j < NJ; ++j)
          acc[4 + i][j] = mfma32(aR[i], bR[j][1], acc[4 + i][j]);
      __builtin_amdgcn_s_setprio(0);
      __builtin_amdgcn_s_barrier();

      // phase 4: A-half1/k0
#pragma unroll
      for (int i = 0; i < 4; ++i) aR[i] = *(const bf16x8*)(Ab + 8192 + i * 2048 + c0);
      __builtin_amdgcn_s_barrier();
      __builtin_amdgcn_s_setprio(1);
#pragma unroll
      for (int i = 0; i < 4; ++i)
#pragma unroll
        for (int j = 0; j < NJ; ++j)
          acc[4 + i][j] = mfma32(aR[i], bR[j][0], acc[4 + i][j]);
      __builtin_amdgcn_s_setprio(0);
      __builtin_amdgcn_s_barrier();

      if (pf) {
        stageA2(kb + 2, cur, 1, 3);          // q1,q3 dead after ph4
        asm volatile("s_waitcnt vmcnt(7)" ::: "memory");
        __builtin_amdgcn_s_barrier();
      } else if (kb + 1 < nkb) {
        asm volatile("s_waitcnt vmcnt(0)" ::: "memory");
        __builtin_amdgcn_s_barrier();
      }
    }
  }

  // ---- epilogue, per-column (tiles straddle Q|K|V boundaries).
  const bool f32out = (flagp != nullptr) && (*flagp == 0);
#pragma unroll
  for (int nj = 0; nj < NJ; ++nj) {
    int cg = colbase + wn * (NJ * 16) + nj * 16 + l16;
    if (vT != nullptr && cg >= 2048) {
      // V section -> per-head transposed store
#pragma unroll
      for (int mi = 0; mi < 8; ++mi) {
        int rg = rowbase + wm * 128 + mi * 16 + quad * 4;
        int b = rg >> 11, n = rg & 2047;
        size_t idx = ((size_t)(b * 1024 + (cg - 2048))) * 2048 + n;
        u16x4 pk;
        pk.x = f2bf(acc[mi][nj][0]); pk.y = f2bf(acc[mi][nj][1]);
        pk.z = f2bf(acc[mi][nj][2]); pk.w = f2bf(acc[mi][nj][3]);
        *(u16x4*)(vT + idx) = pk;
      }
    } else {
      const float scl = (vT != nullptr && cg < 1024) ? CEXP : 1.0f;
      float bv = bias ? bf2f(bias[cg]) : 0.0f;
#pragma unroll
      for (int mi = 0; mi < 8; ++mi) {
#pragma unroll
        for (int r = 0; r < 4; ++r) {
          int rg = rowbase + wm * 128 + mi * 16 + quad * 4 + r;
          float val = acc[mi][nj][r] * scl + bv;
          if (f32out) outF[(size_t)rg * ldc + cg] = val;
          else        C[(size_t)rg * ldc + cg] = f2bf(val);
        }
      }
    }
  }
}

// ---------------------------------------------------------------------------
// Flash attention — 32x32 MFMA structure. Round-6 change: 8 waves x 32 q =
// 256 queries/block (was 4x32=128). Staging/barrier/loop overhead per query
// HALVES: each thread issues 1 K + 1 V async_copy16 per K-tile (was 2+2),
// vmcnt(2) (was 4); K/V staged once per 256 queries. Same 32KB LDS; grid
// (64 bh, 8 qtiles) x 512 thr = 512 blocks = 2 blocks/CU = 16 waves/CU =
// 4/SIMD (same occupancy as before). Ones-MFMA denominator + counted
// staging kept from round 5.
// ---------------------------------------------------------------------------
__global__ __launch_bounds__(512, 2) void attn_fwd(
    const u16* __restrict__ qk, const u16* __restrict__ vT, u16* __restrict__ outp)
{
  __shared__ __align__(16) char sm[32768];  // K[2][8192] | V[2][8192]

  const int t = threadIdx.x;
  const int lane = t & 63, wave = t >> 6;
  const int l31 = lane & 31, h32 = lane >> 5;
  const int bh = blockIdx.x, b = bh >> 4, h = bh & 15;
  const int qtile = blockIdx.y;
  const size_t row0 = (size_t)b * 2048;
  const int qb = qtile * 256 + wave * 32;

  bf16x8 qf[4];
  {
    const u16* qp = qk + (row0 + qb + l31) * 2048 + h * 64 + h32 * 8;
#pragma unroll
    for (int s = 0; s < 4; ++s)
      qf[s] = *(const bf16x8*)(qp + s * 16);
  }

  // staging: thread t covers LDS linear byte t*16 (512 thr x 16B = 8KB tile);
  // row = t>>3, linear col = (t&7)*16; source col pre-swizzled by (row&7)<<4.
  const int srow = t >> 3;
  const int scolb = ((t & 7) << 4) ^ ((srow & 7) << 4);
  const u16* Kg = qk + (row0 + srow) * 2048 + 1024 + h * 64 + (scolb >> 1);
  const u16* Vg = vT + ((size_t)(b * 1024 + h * 64 + srow)) * 2048 + (scolb >> 1);
  const unsigned loff = (unsigned)wave << 10;   // wave-uniform base (+lane*16 HW)

  async_copy16(Kg, sm + loff);
  async_copy16(Vg, sm + 16384 + loff);

  const int swz = (lane & 7) << 4;
  int cswz[4];
#pragma unroll
  for (int s = 0; s < 4; ++s) cswz[s] = (s * 32 + h32 * 16) ^ swz;
  const int rowb = l31 * 128;

  // bf16 1.0 broadcast for the denominator MFMA
  u32x4 onev; onev.x = 0x3F803F80u; onev.y = 0x3F803F80u;
  onev.z = 0x3F803F80u; onev.w = 0x3F803F80u;
  const bf16x8 ones = __builtin_bit_cast(bf16x8, onev);

  f32x16 o2[2] = {};
  f32x16 o3 = {};   // row sums of P (denominator), same layout as o2

  for (int kb = 0; kb < 32; ++kb) {
    const int cur = kb & 1, nxt = cur ^ 1;
    // barrier 1: every wave consumed its reads of buf[nxt] (iter kb-1)
    __builtin_amdgcn_s_barrier();
    if (kb < 31) {
      async_copy16(Kg + (size_t)(kb + 1) * 64 * 2048, sm + nxt * 8192 + loff);
      async_copy16(Vg + (kb + 1) * 64, sm + 16384 + nxt * 8192 + loff);
      asm volatile("s_waitcnt vmcnt(2)" ::: "memory");  // own cur loads landed
    } else {
      asm volatile("s_waitcnt vmcnt(0)" ::: "memory");
    }
    // barrier 2: ALL waves' cur loads landed -> buf[cur] fully resident
    __builtin_amdgcn_s_barrier();

    const char* Kb = sm + cur * 8192;
    const char* Vb = sm + 16384 + cur * 8192;

#pragma unroll
    for (int kh = 0; kh < 2; ++kh) {
      f32x16 s2 = {};
      __builtin_amdgcn_s_setprio(1);
#pragma unroll
      for (int s = 0; s < 4; ++s) {
        bf16x8 kf = *(const bf16x8*)(Kb + kh * 4096 + rowb + cswz[s]);
        s2 = __builtin_amdgcn_mfma_f32_32x32x16_bf16(kf, qf[s], s2, 0, 0, 0);
      }
      __builtin_amdgcn_s_setprio(0);

      u32 u[8];
#pragma unroll
      for (int w = 0; w < 8; ++w) {
        float p0 = fast_exp2(s2[2 * w]);
        float p1 = fast_exp2(s2[2 * w + 1]);
        u[w] = cvt_pk_bf16(p0, p1);
      }

      u32x2 r02 = __builtin_amdgcn_permlane32_swap(u[0], u[2], false, false);
      u32x2 r13 = __builtin_amdgcn_permlane32_swap(u[1], u[3], false, false);
      u32x2 r46 = __builtin_amdgcn_permlane32_swap(u[4], u[6], false, false);
      u32x2 r57 = __builtin_amdgcn_permlane32_swap(u[5], u[7], false, false);
      u32x4 fa0v; fa0v.x = r02.x; fa0v.y = r13.x; fa0v.z = r02.y; fa0v.w = r13.y;
      u32x4 fa1v; fa1v.x = r46.x; fa1v.y = r57.x; fa1v.z = r46.y; fa1v.w = r57.y;
      bf16x8 fa0 = __builtin_bit_cast(bf16x8, fa0v);   // keys kh*32 + 0..15
      bf16x8 fa1 = __builtin_bit_cast(bf16x8, fa1v);   // keys kh*32 + 16..31

      __builtin_amdgcn_s_setprio(1);
#pragma unroll
      for (int eb = 0; eb < 2; ++eb) {
        bf16x8 v0 = *(const bf16x8*)(Vb + eb * 4096 + rowb + cswz[kh * 2 + 0]);
        o2[eb] = __builtin_amdgcn_mfma_f32_32x32x16_bf16(fa0, v0, o2[eb], 0, 0, 0);
        bf16x8 v1 = *(const bf16x8*)(Vb + eb * 4096 + rowb + cswz[kh * 2 + 1]);
        o2[eb] = __builtin_amdgcn_mfma_f32_32x32x16_bf16(fa1, v1, o2[eb], 0, 0, 0);
      }
      // denominator: row sums of P via ones-column (MFMA pipe, no VALU chain)
      o3 = __builtin_amdgcn_mfma_f32_32x32x16_bf16(fa0, ones, o3, 0, 0, 0);
      o3 = __builtin_amdgcn_mfma_f32_32x32x16_bf16(fa1, ones, o3, 0, 0, 0);
      __builtin_amdgcn_s_setprio(0);
    }
  }

  // O layout: col(lane&31) = e, rows = queries (r&3)+8*(r>>2)+4*h32.
  // o3[r] already holds the full denominator for query qr (lane-local).
#pragma unroll
  for (int r = 0; r < 16; ++r) {
    int qr = (r & 3) + 8 * (r >> 2) + 4 * h32;
    float iv = fast_rcp(o3[r]);
    size_t base = (row0 + qb + qr) * 1024 + h * 64 + l31;
    outp[base]      = f2bf(o2[0][r] * iv);
    outp[base + 32] = f2bf(o2[1][r] * iv);
  }
}

// ---------------------------------------------------------------------------
// Workspace (u16 elems): qkbuf 16777216 | vT 8388608 | xb/attn 8388608 |
// wqkvb 3145728 | flag. wprojb/bprojb alias vT after attn_fwd.
// ---------------------------------------------------------------------------
extern "C" void kernel_launch(void* const* d_in, const int* in_sizes, int n_in,
                              void* d_out, int out_size, void* d_ws, size_t ws_size,
                              hipStream_t stream) {
  (void)in_sizes; (void)n_in; (void)out_size; (void)ws_size;
  const void* x_in     = d_in[0];
  const void* wqkv_in  = d_in[1];
  const void* wproj_in = d_in[2];
  const void* bproj_in = d_in[3];

  u16* qkbuf  = (u16*)d_ws;
  u16* vT     = qkbuf + 16777216;
  u16* xb     = vT + 8388608;
  u16* wqkvb  = xb + 8388608;
  int* flag   = (int*)(wqkvb + 3145728);
  u16* attn   = xb;
  u16* wprojb = vT;
  u16* bprojb = vT + 1048576;

  detect_mode<<<1, 256, 0, stream>>>((const u32*)wqkv_in, flag);
  convert_in<<<4096, 256, 0, stream>>>(x_in, xb, flag, 8388608);
  convert_in<<<1536, 256, 0, stream>>>(wqkv_in, wqkvb, flag, 3145728);

  // QKV: 256x192 tiles -> 16x32 = 512 blocks = 2 exact rounds (4-phase).
  gemm_bt<3><<<dim3(16, 32), 512, 0, stream>>>(xb, wqkvb, qkbuf, vT, nullptr,
                                               nullptr, nullptr, 1024, 2048);
  // attn: 256 queries/block -> (64 bh, 8 qtiles) x 512 thr.
  attn_fwd<<<dim3(64, 8), 512, 0, stream>>>(qkbuf, vT, attn);

  convert_in<<<512, 256, 0, stream>>>(wproj_in, wprojb, flag, 1048576);
  convert_in<<<1, 256, 0, stream>>>(bproj_in, bprojb, flag, 1024);

  // proj: 256x128 tiles -> 8x32 = 256 blocks = 1 exact round (2-phase).
  gemm_bt<2><<<dim3(8, 32), 512, 0, stream>>>(attn, wprojb, (u16*)d_out, nullptr,
                                              bprojb, (float*)d_out, flag, 1024, 1024);
}

// Round 7
// 263.997 us; speedup vs baseline: 1.0423x; 1.0206x over previous
//
#include <hip/hip_runtime.h>

typedef unsigned short u16;
typedef unsigned int u32;
typedef __bf16 bf16x8 __attribute__((ext_vector_type(8)));
typedef __bf16 bf16x4 __attribute__((ext_vector_type(4)));
typedef short s16x4 __attribute__((ext_vector_type(4)));
typedef float f32x4 __attribute__((ext_vector_type(4)));
typedef float f32x16 __attribute__((ext_vector_type(16)));
typedef unsigned int u32x2 __attribute__((ext_vector_type(2)));
typedef unsigned int u32x4 __attribute__((ext_vector_type(4)));

struct __align__(8) u16x4 { u16 x, y, z, w; };

__device__ __forceinline__ void async_copy16(const void* g, void* l) {
  __builtin_amdgcn_global_load_lds(
      (__attribute__((address_space(1))) void*)g,
      (__attribute__((address_space(3))) void*)l, 16, 0, 0);
}

__device__ __forceinline__ u16 f2bf(float f) {
  unsigned u = __builtin_bit_cast(unsigned, f);
  u = (u + 0x7FFFu + ((u >> 16) & 1u)) >> 16;
  return (u16)u;
}
__device__ __forceinline__ float bf2f(u16 h) {
  unsigned u = ((unsigned)h) << 16;
  return __builtin_bit_cast(float, u);
}

// NOTE: call amdgcn builtins DIRECTLY — host pass parses aux-target builtins,
// but __has_builtin() is false for them on host (round-3 compile failure).
__device__ __forceinline__ float fast_exp2(float x) {
  return __builtin_amdgcn_exp2f(x);
}
__device__ __forceinline__ float fast_rcp(float x) {
  return __builtin_amdgcn_rcpf(x);
}

__device__ __forceinline__ f32x4 mfma32(bf16x8 a, bf16x8 b, f32x4 c) {
  return __builtin_amdgcn_mfma_f32_16x16x32_bf16(a, b, c, 0, 0, 0);
}

// packed f32 pair -> 1 u32 of 2x bf16 (low = first arg). No builtin on gfx950.
__device__ __forceinline__ u32 cvt_pk_bf16(float lo, float hi) {
  u32 r;
  asm("v_cvt_pk_bf16_f32 %0, %1, %2" : "=v"(r) : "v"(lo), "v"(hi));
  return r;
}

// SCALE * log2(e), folded into Q at the gemm1 epilogue.
#define CEXP 0.18033688011112042f

// ---------------------------------------------------------------------------
// Mode detection (bf16 vs fp32 inputs) — see round-1 notes. flag=0 -> fp32.
// ---------------------------------------------------------------------------
__global__ void detect_mode(const u32* __restrict__ probe, int* __restrict__ flag) {
  __shared__ int cnt[256];
  int t = threadIdx.x;
  int c = 0;
#pragma unroll
  for (int j = 0; j < 16; ++j) {
    u32 v = probe[t + j * 256];
    unsigned e = (v >> 7) & 0xFFu;
    c += (e >= 100u && e <= 130u) ? 1 : 0;
  }
  cnt[t] = c;
  __syncthreads();
  for (int s = 128; s > 0; s >>= 1) {
    if (t < s) cnt[t] += cnt[t + s];
    __syncthreads();
  }
  if (t == 0) *flag = (cnt[0] * 2 > 4096) ? 1 : 0;
}

__global__ void convert_in(const void* __restrict__ src, u16* __restrict__ dst,
                           const int* __restrict__ flag, int n) {
  int mode = *flag;
  int i = (blockIdx.x * blockDim.x + threadIdx.x) * 8;
  if (i >= n) return;
  if (mode == 1) {
    *(uint4*)(dst + i) = *(const uint4*)((const u16*)src + i);
  } else {
    const float* s = (const float*)src;
    float4 a = *(const float4*)(s + i);
    float4 b = *(const float4*)(s + i + 4);
    uint4 o;
    o.x = (u32)f2bf(a.x) | ((u32)f2bf(a.y) << 16);
    o.y = (u32)f2bf(a.z) | ((u32)f2bf(a.w) << 16);
    o.z = (u32)f2bf(b.x) | ((u32)f2bf(b.y) << 16);
    o.w = (u32)f2bf(b.z) | ((u32)f2bf(b.w) << 16);
    *(uint4*)(dst + i) = o;
  }
}

// ---------------------------------------------------------------------------
// NT GEMM, 128x128 tile, BK=64, 256 thr (4 waves 2x2), LDS 64KB ->
// 2 BLOCKS/CU. Round-6 ledger: both GEMMs ran ~60-80us at 1 block/CU with
// ~10 lockstep barriers/K-tile and NO co-resident block to hide sync
// latency (QKV per-K-tile 2.3us vs 0.32us MFMA floor; 3 rounds of phase
// tuning moved nothing -> schedule wasn't the binding constraint,
// co-residency is; m114/m97 lesson + prior session's round-7 conclusion).
// This kernel: NO intra-tile phase barriers (cross-block overlap replaces
// them); K-loop = {16 ds_read_b128 + 32 MFMA compiler-scheduled |
// bar | stage(kb+2) | vmcnt(8) | bar} = 2 barriers/K-tile. T2 XOR swizzle
// (byte ^= (row&7)<<4, both sides) + bijective XCD swizzle kept.
// Grids pack exactly: QKV 24x64=1536 = 3 rounds at 2/CU; proj 8x64=512 =
// 1 round fully co-resident. BN=128 aligns with Q|K|V boundaries (1024/
// 2048) -> whole-tile epilogue branch.
// ---------------------------------------------------------------------------
__global__ __launch_bounds__(256, 2) void gemm_bt(
    const u16* __restrict__ A, const u16* __restrict__ Bm,
    u16* __restrict__ C, u16* __restrict__ vT, const u16* __restrict__ bias,
    float* __restrict__ outF, const int* __restrict__ flagp,
    int K, int ldc)
{
  // A dbuf [2][128][64] @0 (32KB); B dbuf [2][128][64] @32768 (32KB).
  __shared__ __align__(16) char lds[65536];

  const int t = threadIdx.x;
  const int lane = t & 63, wave = t >> 6;
  const int quad = lane >> 4, l16 = lane & 15;
  const int wn = wave & 1, wm = wave >> 1;

  // XCD-chunked bijective remap: blocks with equal rowbase share an XCD.
  const int nwg = gridDim.x * gridDim.y;
  int bid = blockIdx.y * gridDim.x + blockIdx.x;
  bid = (bid & 7) * (nwg >> 3) + (bid >> 3);
  const int rowbase = (bid / gridDim.x) * 128;
  const int colbase = (bid % gridDim.x) * 128;

  // staging: per region, thread t covers LDS linear bytes q*4096 + t*16,
  // q = 0..3 (32 rows each). row = q*32 + (t>>3); linear col = (t&7)*16;
  // global source col pre-swizzled by ((row&7)<<4); q*32 preserves row&7.
  const int srow = t >> 3;
  const int scol = ((t & 7) << 4) ^ ((srow & 7) << 4);
  const int wlds = wave << 10;

  const u16* Arow = A + (size_t)(rowbase + srow) * K + (scol >> 1);
  const u16* Brow = Bm + (size_t)(colbase + srow) * K + (scol >> 1);

  auto stage = [&](int kb_, int buf_) {
#pragma unroll
    for (int q = 0; q < 4; ++q) {
      async_copy16(Arow + (size_t)kb_ * 64 + (size_t)q * 32 * K,
                   lds + buf_ * 16384 + q * 4096 + wlds);
      async_copy16(Brow + (size_t)kb_ * 64 + (size_t)q * 32 * K,
                   lds + 32768 + buf_ * 16384 + q * 4096 + wlds);
    }
  };

  f32x4 acc[4][4] = {};

  // fragment-read bases; row byte-swizzle uses row&7 == l16&7.
  const int swzl = (l16 & 7) << 4;
  const int c0 = (quad * 16) ^ swzl;          // k 0..31
  const int c1 = (64 + quad * 16) ^ swzl;     // k 32..63
  const char* Ard = lds + (size_t)(wm * 64 + l16) * 128;
  const char* Brd = lds + 32768 + (size_t)(wn * 64 + l16) * 128;

  // prologue: tile0 -> buf0, tile1 -> buf1; drain tile0, keep tile1 in flight.
  stage(0, 0);
  stage(1, 1);
  asm volatile("s_waitcnt vmcnt(8)" ::: "memory");
  __builtin_amdgcn_s_barrier();

  const int nkb = K >> 6;
  for (int kb = 0; kb < nkb; ++kb) {
    const int cur = kb & 1;
    const char* Ab = Ard + cur * 16384;
    const char* Bb = Brd + cur * 16384;

    bf16x8 aR[4][2], bR[4][2];
#pragma unroll
    for (int i = 0; i < 4; ++i) {
      aR[i][0] = *(const bf16x8*)(Ab + i * 2048 + c0);
      aR[i][1] = *(const bf16x8*)(Ab + i * 2048 + c1);
    }
#pragma unroll
    for (int j = 0; j < 4; ++j) {
      bR[j][0] = *(const bf16x8*)(Bb + j * 2048 + c0);
      bR[j][1] = *(const bf16x8*)(Bb + j * 2048 + c1);
    }
    __builtin_amdgcn_s_setprio(1);
#pragma unroll
    for (int i = 0; i < 4; ++i)
#pragma unroll
      for (int j = 0; j < 4; ++j) {
        acc[i][j] = mfma32(aR[i][0], bR[j][0], acc[i][j]);
        acc[i][j] = mfma32(aR[i][1], bR[j][1], acc[i][j]);
      }
    __builtin_amdgcn_s_setprio(0);

    if (kb + 1 >= nkb) break;
    __builtin_amdgcn_s_barrier();        // all waves done reading buf[cur]
    if (kb + 2 < nkb) {
      stage(kb + 2, cur);                // 8 loads into just-freed buffer
      asm volatile("s_waitcnt vmcnt(8)" ::: "memory");  // kb+1 landed
    } else {
      asm volatile("s_waitcnt vmcnt(0)" ::: "memory");  // drain final tile
    }
    __builtin_amdgcn_s_barrier();        // buf[nxt] visible to all waves
  }

  // ---- epilogue: whole tile lies in one section (BN=128 aligns bounds).
  if (vT != nullptr && colbase >= 2048) {
    // V section -> per-head transposed store
#pragma unroll
    for (int mi = 0; mi < 4; ++mi) {
      int rg = rowbase + wm * 64 + mi * 16 + quad * 4;
      int b = rg >> 11, n = rg & 2047;
#pragma unroll
      for (int nj = 0; nj < 4; ++nj) {
        int cg = colbase + wn * 64 + nj * 16 + l16;
        size_t idx = ((size_t)(b * 1024 + (cg - 2048))) * 2048 + n;
        u16x4 pk;
        pk.x = f2bf(acc[mi][nj][0]); pk.y = f2bf(acc[mi][nj][1]);
        pk.z = f2bf(acc[mi][nj][2]); pk.w = f2bf(acc[mi][nj][3]);
        *(u16x4*)(vT + idx) = pk;
      }
    }
  } else {
    const bool f32out = (flagp != nullptr) && (*flagp == 0);
    const float scl = (vT != nullptr && colbase < 1024) ? CEXP : 1.0f;
#pragma unroll
    for (int nj = 0; nj < 4; ++nj) {
      int cg = colbase + wn * 64 + nj * 16 + l16;
      float bv = bias ? bf2f(bias[cg]) : 0.0f;
#pragma unroll
      for (int mi = 0; mi < 4; ++mi) {
#pragma unroll
        for (int r = 0; r < 4; ++r) {
          int rg = rowbase + wm * 64 + mi * 16 + quad * 4 + r;
          float val = acc[mi][nj][r] * scl + bv;
          if (f32out) outF[(size_t)rg * ldc + cg] = val;
          else        C[(size_t)rg * ldc + cg] = f2bf(val);
        }
      }
    }
  }
}

// ---------------------------------------------------------------------------
// Flash attention — 32x32 MFMA, 8 waves x 32 q (round-6), unchanged: at
// MfmaUtil 50 + VALUBusy 42 (~92% combined issue) with minimal MFMA/exp2/
// repack counts, this schedule is at its structural ceiling (~892 TF).
// ---------------------------------------------------------------------------
__global__ __launch_bounds__(512, 2) void attn_fwd(
    const u16* __restrict__ qk, const u16* __restrict__ vT, u16* __restrict__ outp)
{
  __shared__ __align__(16) char sm[32768];  // K[2][8192] | V[2][8192]

  const int t = threadIdx.x;
  const int lane = t & 63, wave = t >> 6;
  const int l31 = lane & 31, h32 = lane >> 5;
  const int bh = blockIdx.x, b = bh >> 4, h = bh & 15;
  const int qtile = blockIdx.y;
  const size_t row0 = (size_t)b * 2048;
  const int qb = qtile * 256 + wave * 32;

  bf16x8 qf[4];
  {
    const u16* qp = qk + (row0 + qb + l31) * 2048 + h * 64 + h32 * 8;
#pragma unroll
    for (int s = 0; s < 4; ++s)
      qf[s] = *(const bf16x8*)(qp + s * 16);
  }

  const int srow = t >> 3;
  const int scolb = ((t & 7) << 4) ^ ((srow & 7) << 4);
  const u16* Kg = qk + (row0 + srow) * 2048 + 1024 + h * 64 + (scolb >> 1);
  const u16* Vg = vT + ((size_t)(b * 1024 + h * 64 + srow)) * 2048 + (scolb >> 1);
  const unsigned loff = (unsigned)wave << 10;

  async_copy16(Kg, sm + loff);
  async_copy16(Vg, sm + 16384 + loff);

  const int swz = (lane & 7) << 4;
  int cswz[4];
#pragma unroll
  for (int s = 0; s < 4; ++s) cswz[s] = (s * 32 + h32 * 16) ^ swz;
  const int rowb = l31 * 128;

  u32x4 onev; onev.x = 0x3F803F80u; onev.y = 0x3F803F80u;
  onev.z = 0x3F803F80u; onev.w = 0x3F803F80u;
  const bf16x8 ones = __builtin_bit_cast(bf16x8, onev);

  f32x16 o2[2] = {};
  f32x16 o3 = {};   // row sums of P (denominator), same layout as o2

  for (int kb = 0; kb < 32; ++kb) {
    const int cur = kb & 1, nxt = cur ^ 1;
    __builtin_amdgcn_s_barrier();
    if (kb < 31) {
      async_copy16(Kg + (size_t)(kb + 1) * 64 * 2048, sm + nxt * 8192 + loff);
      async_copy16(Vg + (kb + 1) * 64, sm + 16384 + nxt * 8192 + loff);
      asm volatile("s_waitcnt vmcnt(2)" ::: "memory");
    } else {
      asm volatile("s_waitcnt vmcnt(0)" ::: "memory");
    }
    __builtin_amdgcn_s_barrier();

    const char* Kb = sm + cur * 8192;
    const char* Vb = sm + 16384 + cur * 8192;

#pragma unroll
    for (int kh = 0; kh < 2; ++kh) {
      f32x16 s2 = {};
      __builtin_amdgcn_s_setprio(1);
#pragma unroll
      for (int s = 0; s < 4; ++s) {
        bf16x8 kf = *(const bf16x8*)(Kb + kh * 4096 + rowb + cswz[s]);
        s2 = __builtin_amdgcn_mfma_f32_32x32x16_bf16(kf, qf[s], s2, 0, 0, 0);
      }
      __builtin_amdgcn_s_setprio(0);

      u32 u[8];
#pragma unroll
      for (int w = 0; w < 8; ++w) {
        float p0 = fast_exp2(s2[2 * w]);
        float p1 = fast_exp2(s2[2 * w + 1]);
        u[w] = cvt_pk_bf16(p0, p1);
      }

      u32x2 r02 = __builtin_amdgcn_permlane32_swap(u[0], u[2], false, false);
      u32x2 r13 = __builtin_amdgcn_permlane32_swap(u[1], u[3], false, false);
      u32x2 r46 = __builtin_amdgcn_permlane32_swap(u[4], u[6], false, false);
      u32x2 r57 = __builtin_amdgcn_permlane32_swap(u[5], u[7], false, false);
      u32x4 fa0v; fa0v.x = r02.x; fa0v.y = r13.x; fa0v.z = r02.y; fa0v.w = r13.y;
      u32x4 fa1v; fa1v.x = r46.x; fa1v.y = r57.x; fa1v.z = r46.y; fa1v.w = r57.y;
      bf16x8 fa0 = __builtin_bit_cast(bf16x8, fa0v);   // keys kh*32 + 0..15
      bf16x8 fa1 = __builtin_bit_cast(bf16x8, fa1v);   // keys kh*32 + 16..31

      __builtin_amdgcn_s_setprio(1);
#pragma unroll
      for (int eb = 0; eb < 2; ++eb) {
        bf16x8 v0 = *(const bf16x8*)(Vb + eb * 4096 + rowb + cswz[kh * 2 + 0]);
        o2[eb] = __builtin_amdgcn_mfma_f32_32x32x16_bf16(fa0, v0, o2[eb], 0, 0, 0);
        bf16x8 v1 = *(const bf16x8*)(Vb + eb * 4096 + rowb + cswz[kh * 2 + 1]);
        o2[eb] = __builtin_amdgcn_mfma_f32_32x32x16_bf16(fa1, v1, o2[eb], 0, 0, 0);
      }
      o3 = __builtin_amdgcn_mfma_f32_32x32x16_bf16(fa0, ones, o3, 0, 0, 0);
      o3 = __builtin_amdgcn_mfma_f32_32x32x16_bf16(fa1, ones, o3, 0, 0, 0);
      __builtin_amdgcn_s_setprio(0);
    }
  }

#pragma unroll
  for (int r = 0; r < 16; ++r) {
    int qr = (r & 3) + 8 * (r >> 2) + 4 * h32;
    float iv = fast_rcp(o3[r]);
    size_t base = (row0 + qb + qr) * 1024 + h * 64 + l31;
    outp[base]      = f2bf(o2[0][r] * iv);
    outp[base + 32] = f2bf(o2[1][r] * iv);
  }
}

// ---------------------------------------------------------------------------
// Workspace (u16 elems): qkbuf 16777216 | vT 8388608 | xb/attn 8388608 |
// wqkvb 3145728 | flag. wprojb/bprojb alias vT after attn_fwd.
// ---------------------------------------------------------------------------
extern "C" void kernel_launch(void* const* d_in, const int* in_sizes, int n_in,
                              void* d_out, int out_size, void* d_ws, size_t ws_size,
                              hipStream_t stream) {
  (void)in_sizes; (void)n_in; (void)out_size; (void)ws_size;
  const void* x_in     = d_in[0];
  const void* wqkv_in  = d_in[1];
  const void* wproj_in = d_in[2];
  const void* bproj_in = d_in[3];

  u16* qkbuf  = (u16*)d_ws;
  u16* vT     = qkbuf + 16777216;
  u16* xb     = vT + 8388608;
  u16* wqkvb  = xb + 8388608;
  int* flag   = (int*)(wqkvb + 3145728);
  u16* attn   = xb;
  u16* wprojb = vT;
  u16* bprojb = vT + 1048576;

  detect_mode<<<1, 256, 0, stream>>>((const u32*)wqkv_in, flag);
  convert_in<<<4096, 256, 0, stream>>>(x_in, xb, flag, 8388608);
  convert_in<<<1536, 256, 0, stream>>>(wqkv_in, wqkvb, flag, 3145728);

  // QKV: 128x128 tiles -> 24x64 = 1536 blocks = 3 exact rounds at 2/CU.
  gemm_bt<<<dim3(24, 64), 256, 0, stream>>>(xb, wqkvb, qkbuf, vT, nullptr,
                                            nullptr, nullptr, 1024, 2048);
  // attn: 256 queries/block -> (64 bh, 8 qtiles) x 512 thr.
  attn_fwd<<<dim3(64, 8), 512, 0, stream>>>(qkbuf, vT, attn);

  convert_in<<<512, 256, 0, stream>>>(wproj_in, wprojb, flag, 1048576);
  convert_in<<<1, 256, 0, stream>>>(bproj_in, bprojb, flag, 1024);

  // proj: 128x128 tiles -> 8x64 = 512 blocks = 1 round, co-resident at 2/CU.
  gemm_bt<<<dim3(8, 64), 256, 0, stream>>>(attn, wprojb, (u16*)d_out, nullptr,
                                           bprojb, (float*)d_out, flag, 1024, 1024);
}